// Round 1
// baseline (577.909 us; speedup 1.0000x reference)
//
#include <hip/hip_runtime.h>
#include <stdint.h>

#define Bx 64
#define Tx 2048
#define ENCx 512
#define ATTx 256

typedef float f4 __attribute__((ext_vector_type(4)));
typedef float f32x4 __attribute__((ext_vector_type(4)));
typedef short bf16x8 __attribute__((ext_vector_type(8)));

__device__ __forceinline__ unsigned short f2bf(float f) {
  union { float f; uint32_t u; } c; c.f = f;
  uint32_t u = c.u;
  u += 0x7fffu + ((u >> 16) & 1u);   // RNE
  return (unsigned short)(u >> 16);
}

__device__ __forceinline__ float ftanh(float x) {
  x = fminf(8.f, fmaxf(-8.f, x));
  float z = __expf(2.f * x);
  return 1.f - __fdividef(2.f, z + 1.f);
}

// K0: pack W_enc -> bf16, transposed + chunk-contiguous:
// WTc[(kc*256 + n)*32 + kk] = bf16(W_enc[(kc*32+kk)*256 + n])
__global__ void k0_wt(const float* __restrict__ W, unsigned short* __restrict__ WTc) {
  int tid = blockIdx.x * 256 + threadIdx.x;   // 131072 total
  int kc = tid >> 13;
  int r = tid & 8191;
  int n = r >> 5;
  int kk = r & 31;
  WTc[tid] = f2bf(W[(kc * 32 + kk) * ATTx + n]);
}

// K1: pd[b][a] = dec_hidden[b,:] @ W_dec[:,a]  (fp32)
__global__ void k1_pd(const float* __restrict__ dec, const float* __restrict__ Wd,
                      float* __restrict__ pd) {
  __shared__ float ld[512];
  int b = blockIdx.x, a = threadIdx.x;
  ld[a] = dec[b * 512 + a];
  ld[a + 256] = dec[b * 512 + a + 256];
  __syncthreads();
  float s = 0.f;
#pragma unroll 8
  for (int d = 0; d < 512; ++d) s = fmaf(ld[d], Wd[d * ATTx + a], s);
  pd[b * ATTx + a] = s;
}

// K2: energy[m] = v . tanh(enc[m,:] @ W_enc + pd[b,:])  via bf16 MFMA
// block: 64 rows (one b), 4 waves x 64 cols, K-loop 16 chunks of 32
__global__ __launch_bounds__(256) void k2_energy(
    const float* __restrict__ enc, const unsigned short* __restrict__ WTc,
    const float* __restrict__ pd, const float* __restrict__ v,
    const int* __restrict__ mask, float* __restrict__ energy) {
  __shared__ unsigned short Alds[64 * 40];    // 80B row stride: conflict-free b128
  __shared__ unsigned short Wlds[256 * 40];
  __shared__ float ep[4][64];

  const int tid = threadIdx.x;
  const int wid = tid >> 6;
  const int lane = tid & 63;
  const int q = lane >> 4;
  const int c15 = lane & 15;
  const int m0 = blockIdx.x * 64;
  const int b = m0 >> 11;    // /T

  f32x4 acc[4][4];
#pragma unroll
  for (int i = 0; i < 4; ++i)
#pragma unroll
    for (int j = 0; j < 4; ++j) { f32x4 z = {0.f,0.f,0.f,0.f}; acc[i][j] = z; }

  const int ar = tid >> 2;          // A row 0..63
  const int ak = (tid & 3) * 8;     // A k-offset within chunk
  const int wn = tid >> 2;          // W row base (n = it*64 + wn)
  const int wk = (tid & 3) * 8;

  for (int kc = 0; kc < 16; ++kc) {
    // global loads for this chunk (issue before barrier)
    const f4* ap = (const f4*)(enc + (size_t)(m0 + ar) * ENCx + kc * 32 + ak);
    f4 a0 = ap[0];
    f4 a1 = ap[1];
    uint4 wv[4];
    const uint4* wp = (const uint4*)(WTc + kc * 8192);
#pragma unroll
    for (int it = 0; it < 4; ++it) wv[it] = wp[it * 256 + tid];

    if (kc) __syncthreads();   // previous chunk's frag reads done

    union { unsigned short s[8]; uint4 u; } aw;
    aw.s[0] = f2bf(a0.x); aw.s[1] = f2bf(a0.y); aw.s[2] = f2bf(a0.z); aw.s[3] = f2bf(a0.w);
    aw.s[4] = f2bf(a1.x); aw.s[5] = f2bf(a1.y); aw.s[6] = f2bf(a1.z); aw.s[7] = f2bf(a1.w);
    *(uint4*)&Alds[ar * 40 + ak] = aw.u;
#pragma unroll
    for (int it = 0; it < 4; ++it)
      *(uint4*)&Wlds[(it * 64 + wn) * 40 + wk] = wv[it];
    __syncthreads();

    bf16x8 af[4], bfr[4];
#pragma unroll
    for (int rt = 0; rt < 4; ++rt)
      af[rt] = *(const bf16x8*)&Alds[(rt * 16 + c15) * 40 + q * 8];
#pragma unroll
    for (int ct = 0; ct < 4; ++ct)
      bfr[ct] = *(const bf16x8*)&Wlds[(wid * 64 + ct * 16 + c15) * 40 + q * 8];
#pragma unroll
    for (int rt = 0; rt < 4; ++rt)
#pragma unroll
      for (int ct = 0; ct < 4; ++ct)
        acc[rt][ct] = __builtin_amdgcn_mfma_f32_16x16x32_bf16(af[rt], bfr[ct], acc[rt][ct], 0, 0, 0);
  }

  // epilogue: energy row-reduce.  C/D layout: col = lane&15, row = q*4 + reg
  float part[4][4];
#pragma unroll
  for (int rt = 0; rt < 4; ++rt)
#pragma unroll
    for (int i = 0; i < 4; ++i) part[rt][i] = 0.f;
#pragma unroll
  for (int ct = 0; ct < 4; ++ct) {
    int col = wid * 64 + ct * 16 + c15;
    float pdv = pd[b * ATTx + col];
    float vv = v[col];
#pragma unroll
    for (int rt = 0; rt < 4; ++rt)
#pragma unroll
      for (int i = 0; i < 4; ++i)
        part[rt][i] += ftanh(acc[rt][ct][i] + pdv) * vv;
  }
#pragma unroll
  for (int s = 1; s < 16; s <<= 1)
#pragma unroll
    for (int rt = 0; rt < 4; ++rt)
#pragma unroll
      for (int i = 0; i < 4; ++i)
        part[rt][i] += __shfl_xor(part[rt][i], s, 64);
  if (c15 == 0)
#pragma unroll
    for (int rt = 0; rt < 4; ++rt)
#pragma unroll
      for (int i = 0; i < 4; ++i)
        ep[wid][rt * 16 + q * 4 + i] = part[rt][i];
  __syncthreads();
  if (tid < 64) {
    float e = ep[0][tid] + ep[1][tid] + ep[2][tid] + ep[3][tid];
    int gm = m0 + tid;
    if (mask[gm]) e = -1e30f;   // sentinel, avoids inf-inf NaN
    energy[gm] = e;
  }
}

// K3: per-b softmax over T with dead-row handling (nan_to_num -> 0)
__global__ void k3_softmax(const float* __restrict__ energy, float* __restrict__ attn) {
  __shared__ float redm[4];
  __shared__ float redl[4];
  int b = blockIdx.x, tid = threadIdx.x;
  int lane = tid & 63, wid = tid >> 6;
  float e[8];
#pragma unroll
  for (int i = 0; i < 8; ++i) e[i] = energy[b * Tx + tid + i * 256];
  float m = e[0];
#pragma unroll
  for (int i = 1; i < 8; ++i) m = fmaxf(m, e[i]);
#pragma unroll
  for (int s = 1; s < 64; s <<= 1) m = fmaxf(m, __shfl_xor(m, s, 64));
  if (lane == 0) redm[wid] = m;
  __syncthreads();
  m = fmaxf(fmaxf(redm[0], redm[1]), fmaxf(redm[2], redm[3]));
  bool dead = (m < -1e29f);
  float w[8];
  float l = 0.f;
#pragma unroll
  for (int i = 0; i < 8; ++i) { w[i] = dead ? 0.f : __expf(e[i] - m); l += w[i]; }
#pragma unroll
  for (int s = 1; s < 64; s <<= 1) l += __shfl_xor(l, s, 64);
  if (lane == 0) redl[wid] = l;
  __syncthreads();
  l = redl[0] + redl[1] + redl[2] + redl[3];
  float inv = dead ? 0.f : __fdividef(1.f, l);
#pragma unroll
  for (int i = 0; i < 8; ++i) attn[b * Tx + tid + i * 256] = w[i] * inv;
}

// K4: context partials: part[tc][b][e] = sum_{t in chunk} w[b,t] * enc[b,t,e]
__global__ void k4_ctx(const float* __restrict__ enc, const float* __restrict__ attn,
                       float* __restrict__ part) {
  __shared__ float wl[256];
  __shared__ f4 comb[128];
  int tc = blockIdx.x & 7, b = blockIdx.x >> 3;
  int tid = threadIdx.x;
  wl[tid] = attn[b * Tx + tc * 256 + tid];
  __syncthreads();
  int tl = tid >> 7;
  int ef = tid & 127;
  f4 a = {0.f, 0.f, 0.f, 0.f};
  const f4* base = (const f4*)(enc + ((size_t)b * Tx + tc * 256) * ENCx) + ef;
  for (int t = tl; t < 256; t += 2) {
    float wv = wl[t];
    f4 x = base[(size_t)t * 128];
    a += x * wv;
  }
  if (tl == 1) comb[ef] = a;
  __syncthreads();
  if (tl == 0) {
    a += comb[ef];
    *((f4*)(part + ((size_t)tc * 64 + b) * 512) + ef) = a;
  }
}

// K5: context[b][e] = sum_tc part
__global__ void k5_red(const float* __restrict__ part, float* __restrict__ ctx) {
  int idx = blockIdx.x * 256 + threadIdx.x;   // 32768
  float s = 0.f;
#pragma unroll
  for (int tc = 0; tc < 8; ++tc) s += part[tc * 32768 + idx];
  ctx[idx] = s;
}

extern "C" void kernel_launch(void* const* d_in, const int* in_sizes, int n_in,
                              void* d_out, int out_size, void* d_ws, size_t ws_size,
                              hipStream_t stream) {
  const float* enc   = (const float*)d_in[0];
  const float* dec   = (const float*)d_in[1];
  const int*   mask  = (const int*)d_in[2];
  const float* W_enc = (const float*)d_in[3];
  const float* W_dec = (const float*)d_in[4];
  const float* v     = (const float*)d_in[5];
  float* ctx  = (float*)d_out;          // [64,512]
  float* attn = ctx + Bx * ENCx;        // [64,2048]
  char* ws = (char*)d_ws;
  unsigned short* WTc = (unsigned short*)ws;            // 262144 B
  float* pd     = (float*)(ws + 262144);                // 65536 B
  float* energy = (float*)(ws + 262144 + 65536);        // 524288 B
  float* part   = (float*)(ws + 262144 + 65536 + 524288); // 1 MB

  k0_wt<<<512, 256, 0, stream>>>(W_enc, WTc);
  k1_pd<<<64, 256, 0, stream>>>(dec, W_dec, pd);
  k2_energy<<<2048, 256, 0, stream>>>(enc, WTc, pd, v, mask, energy);
  k3_softmax<<<64, 256, 0, stream>>>(energy, attn);
  k4_ctx<<<512, 256, 0, stream>>>(enc, attn, part);
  k5_red<<<128, 256, 0, stream>>>(part, ctx);
}

// Round 2
// 488.002 us; speedup vs baseline: 1.1842x; 1.1842x over previous
//
#include <hip/hip_runtime.h>
#include <stdint.h>

#define Bx 64
#define Tx 2048
#define ENCx 512
#define ATTx 256

typedef float f4 __attribute__((ext_vector_type(4)));
typedef float f32x4 __attribute__((ext_vector_type(4)));
typedef short bf16x8 __attribute__((ext_vector_type(8)));

__device__ __forceinline__ unsigned short f2bf(float f) {
  union { float f; uint32_t u; } c; c.f = f;
  uint32_t u = c.u;
  u += 0x7fffu + ((u >> 16) & 1u);   // RNE
  return (unsigned short)(u >> 16);
}

// pack two floats -> bf16 pair (round-to-nearest via +0x8000, then v_perm)
__device__ __forceinline__ uint32_t pk_bf(float lo, float hi) {
  uint32_t a = __float_as_uint(lo) + 0x8000u;
  uint32_t b = __float_as_uint(hi) + 0x8000u;
  return __builtin_amdgcn_perm(b, a, 0x07060302u);  // {hi16(b), hi16(a)}
}

__device__ __forceinline__ float ftanh(float x) {
  x = fminf(8.f, fmaxf(-8.f, x));
  float z = __expf(2.f * x);
  return 1.f - __fdividef(2.f, z + 1.f);
}

// K0: pack W_enc -> bf16, transposed + chunk-contiguous:
// WTc[(kc*256 + n)*32 + kk] = bf16(W_enc[(kc*32+kk)*256 + n])
__global__ void k0_wt(const float* __restrict__ W, unsigned short* __restrict__ WTc) {
  int tid = blockIdx.x * 256 + threadIdx.x;   // 131072 total
  int kc = tid >> 13;
  int r = tid & 8191;
  int n = r >> 5;
  int kk = r & 31;
  WTc[tid] = f2bf(W[(kc * 32 + kk) * ATTx + n]);
}

// K1: pd[b][a] = dec_hidden[b,:] @ W_dec[:,a]  (fp32)
__global__ void k1_pd(const float* __restrict__ dec, const float* __restrict__ Wd,
                      float* __restrict__ pd) {
  __shared__ float ld[512];
  int b = blockIdx.x, a = threadIdx.x;
  ld[a] = dec[b * 512 + a];
  ld[a + 256] = dec[b * 512 + a + 256];
  __syncthreads();
  float s = 0.f;
#pragma unroll 8
  for (int d = 0; d < 512; ++d) s = fmaf(ld[d], Wd[d * ATTx + a], s);
  pd[b * ATTx + a] = s;
}

// K2: energy[m] = v . tanh(enc[m,:] @ W_enc + pd[b,:])
// Barrier-free main loop: each wave owns 32 rows; A global->reg->bf16,
// B fragments straight from L2-resident packed WTc. 32 MFMA / k-chunk.
__global__ __launch_bounds__(256) void k2_energy(
    const float* __restrict__ enc, const unsigned short* __restrict__ WTc,
    const float* __restrict__ pd, const float* __restrict__ v,
    const int* __restrict__ mask, float* __restrict__ energy) {
  __shared__ float pdv[256];
  __shared__ float vvs[256];
  const int tid = threadIdx.x;
  const int wid = tid >> 6;
  const int lane = tid & 63;
  const int q = lane >> 4;       // k-quad
  const int c15 = lane & 15;     // row (A) / col (B,C)
  const int m0 = blockIdx.x * 128;       // 128 rows per block
  const int b = m0 >> 11;                // all rows same batch (T=2048 | 128)

  pdv[tid] = pd[b * ATTx + tid];
  vvs[tid] = v[tid];
  __syncthreads();   // only barrier in the kernel

  const int mrow = m0 + wid * 32 + c15;
  const float* a0p = enc + (size_t)mrow * ENCx + q * 8;          // rows mt=0
  const float* a1p = a0p + 16 * ENCx;                            // rows mt=1
  const unsigned short* wb = WTc + c15 * 32 + q * 8;

  f32x4 acc[2][16];
#pragma unroll
  for (int mt = 0; mt < 2; ++mt)
#pragma unroll
    for (int ct = 0; ct < 16; ++ct) { f32x4 z = {0.f,0.f,0.f,0.f}; acc[mt][ct] = z; }

  for (int kc = 0; kc < 16; ++kc) {
    f4 x0 = *(const f4*)(a0p + kc * 32);
    f4 x1 = *(const f4*)(a0p + kc * 32 + 4);
    f4 y0 = *(const f4*)(a1p + kc * 32);
    f4 y1 = *(const f4*)(a1p + kc * 32 + 4);
    bf16x8 bfr[16];
    const unsigned short* wkc = wb + kc * 8192;
#pragma unroll
    for (int ct = 0; ct < 16; ++ct)
      bfr[ct] = *(const bf16x8*)(wkc + ct * 512);

    union { uint32_t u[4]; bf16x8 v; } am0, am1;
    am0.u[0] = pk_bf(x0.x, x0.y); am0.u[1] = pk_bf(x0.z, x0.w);
    am0.u[2] = pk_bf(x1.x, x1.y); am0.u[3] = pk_bf(x1.z, x1.w);
    am1.u[0] = pk_bf(y0.x, y0.y); am1.u[1] = pk_bf(y0.z, y0.w);
    am1.u[2] = pk_bf(y1.x, y1.y); am1.u[3] = pk_bf(y1.z, y1.w);

#pragma unroll
    for (int ct = 0; ct < 16; ++ct) {
      acc[0][ct] = __builtin_amdgcn_mfma_f32_16x16x32_bf16(am0.v, bfr[ct], acc[0][ct], 0, 0, 0);
      acc[1][ct] = __builtin_amdgcn_mfma_f32_16x16x32_bf16(am1.v, bfr[ct], acc[1][ct], 0, 0, 0);
    }
  }

  // epilogue: C/D layout col = c15, row = q*4 + i (within 16x16 tile)
  float ps[2][4];
#pragma unroll
  for (int mt = 0; mt < 2; ++mt)
#pragma unroll
    for (int i = 0; i < 4; ++i) ps[mt][i] = 0.f;
#pragma unroll
  for (int ct = 0; ct < 16; ++ct) {
    float pv = pdv[ct * 16 + c15];
    float vv = vvs[ct * 16 + c15];
#pragma unroll
    for (int mt = 0; mt < 2; ++mt)
#pragma unroll
      for (int i = 0; i < 4; ++i)
        ps[mt][i] += ftanh(acc[mt][ct][i] + pv) * vv;
  }
#pragma unroll
  for (int s = 1; s < 16; s <<= 1)
#pragma unroll
    for (int mt = 0; mt < 2; ++mt)
#pragma unroll
      for (int i = 0; i < 4; ++i)
        ps[mt][i] += __shfl_xor(ps[mt][i], s, 64);
  if (c15 == 0) {
#pragma unroll
    for (int mt = 0; mt < 2; ++mt)
#pragma unroll
      for (int i = 0; i < 4; ++i) {
        int gm = m0 + wid * 32 + mt * 16 + q * 4 + i;
        energy[gm] = mask[gm] ? -1e30f : ps[mt][i];
      }
  }
}

// K3: per-b softmax over T with dead-row handling (nan_to_num -> 0)
__global__ void k3_softmax(const float* __restrict__ energy, float* __restrict__ attn) {
  __shared__ float redm[4];
  __shared__ float redl[4];
  int b = blockIdx.x, tid = threadIdx.x;
  int lane = tid & 63, wid = tid >> 6;
  float e[8];
#pragma unroll
  for (int i = 0; i < 8; ++i) e[i] = energy[b * Tx + tid + i * 256];
  float m = e[0];
#pragma unroll
  for (int i = 1; i < 8; ++i) m = fmaxf(m, e[i]);
#pragma unroll
  for (int s = 1; s < 64; s <<= 1) m = fmaxf(m, __shfl_xor(m, s, 64));
  if (lane == 0) redm[wid] = m;
  __syncthreads();
  m = fmaxf(fmaxf(redm[0], redm[1]), fmaxf(redm[2], redm[3]));
  bool dead = (m < -1e29f);
  float w[8];
  float l = 0.f;
#pragma unroll
  for (int i = 0; i < 8; ++i) { w[i] = dead ? 0.f : __expf(e[i] - m); l += w[i]; }
#pragma unroll
  for (int s = 1; s < 64; s <<= 1) l += __shfl_xor(l, s, 64);
  if (lane == 0) redl[wid] = l;
  __syncthreads();
  l = redl[0] + redl[1] + redl[2] + redl[3];
  float inv = dead ? 0.f : __fdividef(1.f, l);
#pragma unroll
  for (int i = 0; i < 8; ++i) attn[b * Tx + tid + i * 256] = w[i] * inv;
}

// K4: context partials over 16 T-chunks of 128:
// part[tc][b][e] = sum_{t in chunk} w[b,t] * enc[b,t,e]
__global__ void k4_ctx(const float* __restrict__ enc, const float* __restrict__ attn,
                       float* __restrict__ part) {
  __shared__ float wl[128];
  __shared__ f4 comb[128];
  int tc = blockIdx.x & 15, b = blockIdx.x >> 4;
  int tid = threadIdx.x;
  if (tid < 128) wl[tid] = attn[b * Tx + tc * 128 + tid];
  __syncthreads();
  int tl = tid >> 7;
  int ef = tid & 127;
  f4 a = {0.f, 0.f, 0.f, 0.f};
  const f4* base = (const f4*)(enc + ((size_t)b * Tx + tc * 128) * ENCx) + ef;
  for (int t = tl; t < 128; t += 2) {
    f4 x = base[(size_t)t * 128];
    a += x * wl[t];
  }
  if (tl == 1) comb[ef] = a;
  __syncthreads();
  if (tl == 0) {
    a += comb[ef];
    *((f4*)(part + ((size_t)tc * 64 + b) * 512) + ef) = a;
  }
}

// K5: context[b][e] = sum_tc part
__global__ void k5_red(const float* __restrict__ part, float* __restrict__ ctx) {
  int idx = blockIdx.x * 256 + threadIdx.x;   // 32768
  float s = 0.f;
#pragma unroll
  for (int tc = 0; tc < 16; ++tc) s += part[tc * 32768 + idx];
  ctx[idx] = s;
}

extern "C" void kernel_launch(void* const* d_in, const int* in_sizes, int n_in,
                              void* d_out, int out_size, void* d_ws, size_t ws_size,
                              hipStream_t stream) {
  const float* enc   = (const float*)d_in[0];
  const float* dec   = (const float*)d_in[1];
  const int*   mask  = (const int*)d_in[2];
  const float* W_enc = (const float*)d_in[3];
  const float* W_dec = (const float*)d_in[4];
  const float* v     = (const float*)d_in[5];
  float* ctx  = (float*)d_out;          // [64,512]
  float* attn = ctx + Bx * ENCx;        // [64,2048]
  char* ws = (char*)d_ws;
  unsigned short* WTc = (unsigned short*)ws;              // 262144 B
  float* pd     = (float*)(ws + 262144);                  // 65536 B
  float* energy = (float*)(ws + 262144 + 65536);          // 524288 B
  float* part   = (float*)(ws + 262144 + 65536 + 524288); // 2 MB

  k0_wt<<<512, 256, 0, stream>>>(W_enc, WTc);
  k1_pd<<<64, 256, 0, stream>>>(dec, W_dec, pd);
  k2_energy<<<1024, 256, 0, stream>>>(enc, WTc, pd, v, mask, energy);
  k3_softmax<<<64, 256, 0, stream>>>(energy, attn);
  k4_ctx<<<1024, 256, 0, stream>>>(enc, attn, part);
  k5_red<<<128, 256, 0, stream>>>(part, ctx);
}